// Round 5
// baseline (1173.979 us; speedup 1.0000x reference)
//
#include <hip/hip_runtime.h>
#include <cstdio>
#include <cstdint>

#define LRELU 0.2f
#define BN_EPS 1e-5f

typedef short bf16x8 __attribute__((ext_vector_type(8)));
typedef float f32x4 __attribute__((ext_vector_type(4)));
typedef float f32x2 __attribute__((ext_vector_type(2)));

__device__ inline unsigned short f2bf(float f) {
  unsigned int u = __float_as_uint(f);
  u += 0x7fffu + ((u >> 16) & 1u);   // RNE
  return (unsigned short)(u >> 16);
}
__device__ inline float bf2f(unsigned short v) {
  return __uint_as_float(((unsigned int)v) << 16);
}
__device__ inline float bflo(unsigned int u) { return __uint_as_float(u << 16); }
__device__ inline float bfhi(unsigned int u) { return __uint_as_float(u & 0xffff0000u); }

// =========== CSR build (bucketed: bucket = dst>>8, NB = ceil(N/256)) ========

__global__ __launch_bounds__(256) void k_bhist_copy(const int* __restrict__ dst,
                                                    int* __restrict__ bh,
                                                    const float4* __restrict__ ea,
                                                    float4* __restrict__ oea,
                                                    int E) {
  __shared__ int cnt[512];
  for (int b = threadIdx.x; b < 512; b += 256) cnt[b] = 0;
  __syncthreads();
  const int gid = blockIdx.x * blockDim.x + threadIdx.x;
  const int gstride = gridDim.x * blockDim.x;
  for (int i = gid; i < E; i += gstride) atomicAdd(&cnt[dst[i] >> 8], 1);
  // fused edge_attr passthrough (independent data, hides under atomics)
  const int n4 = E * 2;
  for (int i = gid; i < n4; i += gstride) oea[i] = ea[i];
  __syncthreads();
  for (int b = threadIdx.x; b < 512; b += 256)
    if (cnt[b]) atomicAdd(&bh[b], cnt[b]);
}

__global__ __launch_bounds__(512) void k_exscan(const int* __restrict__ bh,
                                                int* __restrict__ bstart,
                                                int* __restrict__ bcur, int n,
                                                int* __restrict__ offsN) {
  __shared__ int sh[512];
  const int t = threadIdx.x;
  int v = (t < n) ? bh[t] : 0;
  sh[t] = v;
  __syncthreads();
  for (int s = 1; s < 512; s <<= 1) {
    int u = (t >= s) ? sh[t - s] : 0;
    __syncthreads();
    sh[t] += u;
    __syncthreads();
  }
  if (t < n) {
    int ex = sh[t] - v;
    bstart[t] = ex;
    bcur[t] = ex;
  }
  if (t == n - 1) {
    bstart[n] = sh[t];
    *offsN = sh[t];
  }
}

__global__ __launch_bounds__(256) void k_bscatter(const int* __restrict__ src,
                                                  const int* __restrict__ dst,
                                                  int* __restrict__ bcur,
                                                  uint2* __restrict__ bpair, int E) {
  __shared__ int cnt[512];
  const int chunk = (E + gridDim.x - 1) / gridDim.x;
  const int beg = blockIdx.x * chunk;
  const int end = min(E, beg + chunk);
  for (int b = threadIdx.x; b < 512; b += 256) cnt[b] = 0;
  __syncthreads();
  for (int e = beg + threadIdx.x; e < end; e += 256)
    atomicAdd(&cnt[dst[e] >> 8], 1);
  __syncthreads();
  for (int b = threadIdx.x; b < 512; b += 256) {
    int c = cnt[b];
    cnt[b] = (c > 0) ? atomicAdd(&bcur[b], c) : 0;
  }
  __syncthreads();
  for (int e = beg + threadIdx.x; e < end; e += 256) {
    int d = dst[e];
    int pos = atomicAdd(&cnt[d >> 8], 1);
    bpair[pos] = make_uint2((unsigned)src[e], (unsigned)d);
  }
}

// per-bucket: LDS hist of 256 dsts -> LDS scan -> offs + placement
__global__ __launch_bounds__(256) void k_bcsr2(const uint2* __restrict__ bpair,
                                               const int* __restrict__ bstart,
                                               int* __restrict__ offs,
                                               int* __restrict__ srcs, int N) {
  __shared__ int sc[256];
  __shared__ int cur[256];
  const int b = blockIdx.x;
  const int lo = b << 8;
  const int t = threadIdx.x;
  const int e0 = bstart[b], e1 = bstart[b + 1];
  sc[t] = 0;
  __syncthreads();
  for (int e = e0 + t; e < e1; e += 256) atomicAdd(&sc[bpair[e].y & 255], 1);
  __syncthreads();
  int v = sc[t];
  for (int s = 1; s < 256; s <<= 1) {
    int u = (t >= s) ? sc[t - s] : 0;
    __syncthreads();
    sc[t] += u;
    __syncthreads();
  }
  const int pos0 = e0 + sc[t] - v;   // exclusive
  cur[t] = pos0;
  if (lo + t < N) offs[lo + t] = pos0;
  __syncthreads();
  for (int e = e0 + t; e < e1; e += 256) {
    uint2 p = bpair[e];
    int pos = atomicAdd(&cur[p.y & 255], 1);
    srcs[pos] = (int)p.x;
  }
}

// ====== weight cast+transpose (all 3 layers, one launch) ====================
__global__ void k_castW3(const float* __restrict__ W0, const float* __restrict__ W1,
                         const float* __restrict__ W2,
                         unsigned short* __restrict__ Wt0,
                         unsigned short* __restrict__ Wt1,
                         unsigned short* __restrict__ Wt2) {
  int o = blockIdx.x * 256 + threadIdx.x;   // 16384 + 4096 + 4096 = 24576
  if (o < 16384) {
    int n = o >> 7, k = o & 127;
    Wt0[o] = f2bf(W0[k * 128 + n]);
  } else if (o < 20480) {
    int p = o - 16384, n = p >> 5, k = p & 31;
    Wt1[p] = f2bf(W1[k * 128 + n]);
  } else if (o < 24576) {
    int p = o - 20480, n = p >> 5, k = p & 31;
    Wt2[p] = f2bf(W2[k * 128 + n]);
  }
}

// ====== MFMA GEMM + fused attention logits (+ optional fused BN+ReLU) =======
// Writes h CHANNEL-SLICED: hs[slice=ch>>4][node][16 ch] (3.2 MB per slice so
// one slice fits an XCD's 4 MB L2 in k_gat). als/ald written head-major [4][N].
template <int K, bool BN>
__global__ __launch_bounds__(256) void k_mfma(
    const float* __restrict__ Ain, const unsigned short* __restrict__ Wt,
    const float* __restrict__ asrc, const float* __restrict__ adst,
    const float* __restrict__ stats, const float* __restrict__ g,
    const float* __restrict__ be,
    unsigned short* __restrict__ h, float* __restrict__ als,
    float* __restrict__ ald, int N) {
  __shared__ unsigned short lsh[4][16 * 132];
  __shared__ float sc_s[32], sh_s[32];
  const int wv   = threadIdx.x >> 6;
  const int lane = threadIdx.x & 63;
  const int quad = lane >> 4;
  const int col  = lane & 15;
  const int m0   = blockIdx.x * 64 + wv * 16;
  const int rowc = min(m0 + col, N - 1);

  if constexpr (BN) {
    if (threadIdx.x < 32) {
      float s = 0.f, ss = 0.f;
#pragma unroll
      for (int r = 0; r < 8; r++) {
        s  += stats[r * 64 + threadIdx.x];
        ss += stats[r * 64 + 32 + threadIdx.x];
      }
      const float inv = 1.f / (float)N;
      const float mu = s * inv;
      const float var = ss * inv - mu * mu;   // biased, as in ref
      const float scv = g[threadIdx.x] * rsqrtf(var + BN_EPS);
      sc_s[threadIdx.x] = scv;
      sh_s[threadIdx.x] = be[threadIdx.x] - mu * scv;
    }
    __syncthreads();
  }

  f32x4 acc[8];
#pragma unroll
  for (int t = 0; t < 8; t++) acc[t] = (f32x4){0.f, 0.f, 0.f, 0.f};

#pragma unroll
  for (int ks = 0; ks < K / 32; ks++) {
    const int k0 = ks * 32 + quad * 8;
    const float* ap = Ain + (size_t)rowc * K + k0;
    float4 f0 = *(const float4*)ap;
    float4 f1 = *(const float4*)(ap + 4);
    bf16x8 a;
    if constexpr (BN) {
      f0.x = fmaxf(0.f, fmaf(f0.x, sc_s[k0 + 0], sh_s[k0 + 0]));
      f0.y = fmaxf(0.f, fmaf(f0.y, sc_s[k0 + 1], sh_s[k0 + 1]));
      f0.z = fmaxf(0.f, fmaf(f0.z, sc_s[k0 + 2], sh_s[k0 + 2]));
      f0.w = fmaxf(0.f, fmaf(f0.w, sc_s[k0 + 3], sh_s[k0 + 3]));
      f1.x = fmaxf(0.f, fmaf(f1.x, sc_s[k0 + 4], sh_s[k0 + 4]));
      f1.y = fmaxf(0.f, fmaf(f1.y, sc_s[k0 + 5], sh_s[k0 + 5]));
      f1.z = fmaxf(0.f, fmaf(f1.z, sc_s[k0 + 6], sh_s[k0 + 6]));
      f1.w = fmaxf(0.f, fmaf(f1.w, sc_s[k0 + 7], sh_s[k0 + 7]));
    }
    a[0] = (short)f2bf(f0.x); a[1] = (short)f2bf(f0.y);
    a[2] = (short)f2bf(f0.z); a[3] = (short)f2bf(f0.w);
    a[4] = (short)f2bf(f1.x); a[5] = (short)f2bf(f1.y);
    a[6] = (short)f2bf(f1.z); a[7] = (short)f2bf(f1.w);
#pragma unroll
    for (int t = 0; t < 8; t++) {
      bf16x8 b = *(const bf16x8*)(Wt + (size_t)(t * 16 + col) * K + k0);
      acc[t] = __builtin_amdgcn_mfma_f32_16x16x32_bf16(a, b, acc[t], 0, 0, 0);
    }
  }

#pragma unroll
  for (int t = 0; t < 8; t++) {
#pragma unroll
    for (int j = 0; j < 4; j++)
      lsh[wv][(quad * 4 + j) * 132 + col + 16 * t] = f2bf(acc[t][j]);
  }
  __syncthreads();

  float as8[8], ad8[8];
#pragma unroll
  for (int j = 0; j < 8; j++) {
    as8[j] = asrc[col * 8 + j];
    ad8[j] = adst[col * 8 + j];
  }

#pragma unroll
  for (int i = 0; i < 4; i++) {
    const int row = i * 4 + quad;
    const int hrow = m0 + row;
    const unsigned short* rp = &lsh[wv][row * 132 + col * 8];
    ushort4 lo = *(const ushort4*)rp;
    ushort4 hi = *(const ushort4*)(rp + 4);
    float p = 0.f, q = 0.f, v;
    v = bf2f(lo.x); p += v * as8[0]; q += v * ad8[0];
    v = bf2f(lo.y); p += v * as8[1]; q += v * ad8[1];
    v = bf2f(lo.z); p += v * as8[2]; q += v * ad8[2];
    v = bf2f(lo.w); p += v * as8[3]; q += v * ad8[3];
    v = bf2f(hi.x); p += v * as8[4]; q += v * ad8[4];
    v = bf2f(hi.y); p += v * as8[5]; q += v * ad8[5];
    v = bf2f(hi.z); p += v * as8[6]; q += v * ad8[6];
    v = bf2f(hi.w); p += v * as8[7]; q += v * ad8[7];
    if (hrow < N) {
      // sliced write: channels col*8..col*8+7 live in slice col>>1,
      // within-slice offset (col&1)*8
      const int qs = col >> 1;
      unsigned short* gp = h + (size_t)qs * N * 16 + (size_t)hrow * 16 + (col & 1) * 8;
      ((ushort4*)gp)[0] = lo;
      ((ushort4*)gp)[1] = hi;
    }
    p += __shfl_xor(p, 1); p += __shfl_xor(p, 2);
    q += __shfl_xor(q, 1); q += __shfl_xor(q, 2);
    if ((lane & 3) == 0 && hrow < N) {
      const int head = col >> 2;
      als[(size_t)head * N + hrow] = p;   // head-major
      ald[(size_t)head * N + hrow] = q;
    }
  }
}

// ====== per-dst aggregation, channel-sliced ================================
// Grid = 8 slices x node-chunks; slice = blockIdx.x & 7 so round-robin block
// dispatch pins slice s to XCD s: each XCD re-reads ONLY its 3.2 MB h-slice
// (L2-resident) instead of all 25.6 MB. srcs are nontemporal (streaming,
// don't evict the slice). Wave = 8 edge-slots x 8 ch-pairs; per-slot src
// broadcast via shfl. Writes f32 per-slice partials ysl[slice][node][16].
#define NPB 16   // nodes per block (4 per wave)
__global__ __launch_bounds__(256) void k_gat(
    const unsigned int* __restrict__ hs,   // [8][N][8] uints = 16 ch bf16
    const float* __restrict__ alsh,        // [4][N]
    const float* __restrict__ aldh,        // [4][N]
    const int* __restrict__ offs,
    const int* __restrict__ srcs,
    float* __restrict__ ysl,               // [8][N][16] f32
    int N) {
  const int slice = blockIdx.x & 7;
  const int head  = slice >> 1;
  const int chunk = blockIdx.x >> 3;
  const int wv    = threadIdx.x >> 6;
  const int lane  = threadIdx.x & 63;
  const int slot  = lane >> 3;     // edge slot 0..7
  const int chp   = lane & 7;      // channel pair 0..7 (2 ch each)
  const unsigned int* __restrict__ hb = hs + (size_t)slice * N * 8;
  const float* __restrict__ alh = alsh + (size_t)head * N;
  float* __restrict__ yb = ysl + (size_t)slice * N * 16;

  for (int ni = 0; ni < 4; ni++) {
    const int node = chunk * NPB + wv * 4 + ni;
    if (node >= N) break;
    const int beg = __builtin_amdgcn_readfirstlane(offs[node]);
    const int end = __builtin_amdgcn_readfirstlane(offs[node + 1]);
    const float ad = aldh[(size_t)head * N + node];
    float a0 = 0.f, a1 = 0.f, dn = 0.f;

    for (int base = beg; base < end; base += 64) {
      const int m = min(64, end - base);
      const int sv = __builtin_nontemporal_load(&srcs[base + min(lane, m - 1)]);
      for (int j0 = 0; j0 < m; j0 += 8) {
        const int j = j0 + slot;
        const int s = __shfl(sv, min(j, m - 1));
        const float al = alh[s];
        const unsigned int u = hb[(size_t)s * 8 + chp];
        float e = al + ad;
        e = fmaxf(e, LRELU * e);
        float w = __expf(e);
        w = (j < m) ? w : 0.f;
        dn += w;
        a0 = fmaf(w, bflo(u), a0);
        a1 = fmaf(w, bfhi(u), a1);
      }
    }
    // reduce over edge slots (lane bits 3..5)
    dn += __shfl_xor(dn, 8);  a0 += __shfl_xor(a0, 8);  a1 += __shfl_xor(a1, 8);
    dn += __shfl_xor(dn, 16); a0 += __shfl_xor(a0, 16); a1 += __shfl_xor(a1, 16);
    dn += __shfl_xor(dn, 32); a0 += __shfl_xor(a0, 32); a1 += __shfl_xor(a1, 32);
    if (lane < 8) {
      const float r = (dn > 0.f) ? (1.f / dn) : 0.f;
      f32x2 o;
      o[0] = a0 * r;
      o[1] = a1 * r;
      __builtin_nontemporal_store(o, (f32x2*)(yb + (size_t)node * 16 + chp * 2));
    }
  }
}

// ====== head-reduce: y[n][c] = 0.25 * sum_h P[2h + (c>>4)][n][c&15] + bias ==
// Streaming; fuses BN stats (8-way replicated atomic flush).
template <bool STATS>
__global__ __launch_bounds__(256) void k_red(
    const float* __restrict__ ysl, const float* __restrict__ bias,
    float* __restrict__ y, float* __restrict__ stats, int N) {
  __shared__ float s1[32], s2[32];
  if constexpr (STATS) {
    if (threadIdx.x < 32) { s1[threadIdx.x] = 0.f; s2[threadIdx.x] = 0.f; }
    __syncthreads();
  }
  const int gidx = blockIdx.x * 256 + threadIdx.x;
  const int node = gidx >> 3;
  const int cg = gidx & 7;        // channel group of 4: c0 = cg*4
  if (node < N) {
    const int hi = cg >> 2;       // which 16-ch half
    const int off = (cg & 3) * 4; // within-slice channel offset
    float4 s = {0.f, 0.f, 0.f, 0.f};
#pragma unroll
    for (int hh = 0; hh < 4; hh++) {
      const float4 p = *(const float4*)(ysl +
          ((size_t)(hh * 2 + hi) * N + node) * 16 + off);
      s.x += p.x; s.y += p.y; s.z += p.z; s.w += p.w;
    }
    const float4 b4 = *(const float4*)(bias + cg * 4);
    float4 o;
    o.x = 0.25f * s.x + b4.x;
    o.y = 0.25f * s.y + b4.y;
    o.z = 0.25f * s.z + b4.z;
    o.w = 0.25f * s.w + b4.w;
    *(float4*)(y + (size_t)node * 32 + cg * 4) = o;
    if constexpr (STATS) {
      atomicAdd(&s1[cg * 4 + 0], o.x); atomicAdd(&s2[cg * 4 + 0], o.x * o.x);
      atomicAdd(&s1[cg * 4 + 1], o.y); atomicAdd(&s2[cg * 4 + 1], o.y * o.y);
      atomicAdd(&s1[cg * 4 + 2], o.z); atomicAdd(&s2[cg * 4 + 2], o.z * o.z);
      atomicAdd(&s1[cg * 4 + 3], o.w); atomicAdd(&s2[cg * 4 + 3], o.w * o.w);
    }
  }
  if constexpr (STATS) {
    __syncthreads();
    if (threadIdx.x < 32) {
      float* sb = stats + (blockIdx.x & 7) * 64;
      atomicAdd(&sb[threadIdx.x], s1[threadIdx.x]);
      atomicAdd(&sb[32 + threadIdx.x], s2[threadIdx.x]);
    }
  }
}

// ---------------- launch ----------------
extern "C" void kernel_launch(void* const* d_in, const int* in_sizes, int n_in,
                              void* d_out, int out_size, void* d_ws, size_t ws_size,
                              hipStream_t stream) {
  const float* x   = (const float*)d_in[0];
  const int*   ei  = (const int*)d_in[1];
  const float* ea  = (const float*)d_in[2];
  const float* W0  = (const float*)d_in[3];
  const float* as0 = (const float*)d_in[4];
  const float* ad0 = (const float*)d_in[5];
  const float* b0  = (const float*)d_in[6];
  const float* g0  = (const float*)d_in[7];
  const float* be0 = (const float*)d_in[8];
  const float* W1  = (const float*)d_in[9];
  const float* as1 = (const float*)d_in[10];
  const float* ad1 = (const float*)d_in[11];
  const float* b1  = (const float*)d_in[12];
  const float* g1  = (const float*)d_in[13];
  const float* be1 = (const float*)d_in[14];
  const float* W2  = (const float*)d_in[15];
  const float* as2 = (const float*)d_in[16];
  const float* ad2 = (const float*)d_in[17];
  const float* b2  = (const float*)d_in[18];

  const int N = in_sizes[0] / 128;
  const int E = in_sizes[1] / 2;
  const int* srcI = ei;
  const int* dstI = ei + E;
  const int NB = (N + 255) >> 8;

  char* w = (char*)d_ws;
  auto carve = [&](size_t bytes) -> void* {
    void* p = (void*)w;
    w += (bytes + 255) & ~(size_t)255;
    return p;
  };
  unsigned short* h  = (unsigned short*)carve((size_t)N * 128 * 2); // sliced hs
  float* als        = (float*)carve((size_t)N * 4 * 4);   // head-major [4][N]
  float* ald        = (float*)carve((size_t)N * 4 * 4);   // head-major [4][N]
  float* y          = (float*)carve((size_t)N * 32 * 4);
  float* ysl        = (float*)carve((size_t)N * 8 * 16 * 4); // 51.2 MB partials
  int* offs         = (int*)carve((size_t)(N + 1) * 4);
  int* srcs         = (int*)carve((size_t)E * 4);
  // zero-init region: bh + stats covered by ONE small memset (6 KB)
  int* bh           = (int*)carve(512 * 4);
  float* stats      = (float*)carve(1024 * 4);   // 2 layers x 8 replicas x 64
  char* zend        = w;
  int* bstart       = (int*)carve(513 * 4);
  int* bcur         = (int*)carve(512 * 4);
  unsigned short* Wt0 = (unsigned short*)carve(128 * 128 * 2);
  unsigned short* Wt1 = (unsigned short*)carve(128 * 32 * 2);
  unsigned short* Wt2 = (unsigned short*)carve(128 * 32 * 2);
  if ((size_t)(w - (char*)d_ws) > ws_size) {
    fprintf(stderr, "GAT kernel: ws too small (%zu needed, %zu given)\n",
            (size_t)(w - (char*)d_ws), ws_size);
    return;
  }
  uint2* bpair = (uint2*)h;   // aliases h; consumed before h is written

  float* out_nodes = (float*)d_out;
  float* out_ea    = out_nodes + (size_t)N * 32;

  (void)hipMemsetAsync(bh, 0, (size_t)(zend - (char*)bh), stream);

  k_bhist_copy<<<256, 256, 0, stream>>>(dstI, bh, (const float4*)ea,
                                        (float4*)out_ea, E);
  k_exscan<<<1, 512, 0, stream>>>(bh, bstart, bcur, NB, offs + N);
  k_bscatter<<<128, 256, 0, stream>>>(srcI, dstI, bcur, bpair, E);
  k_bcsr2<<<NB, 256, 0, stream>>>(bpair, bstart, offs, srcs, N);

  k_castW3<<<96, 256, 0, stream>>>(W0, W1, W2, Wt0, Wt1, Wt2);

  const int gGemm = (N + 63) / 64;
  const int gGat  = 8 * ((N + NPB - 1) / NPB);
  const int gRed  = (N * 8 + 255) / 256;

  // layer 0
  k_mfma<128, false><<<gGemm, 256, 0, stream>>>(x, Wt0, as0, ad0,
                                                nullptr, nullptr, nullptr,
                                                h, als, ald, N);
  k_gat<<<gGat, 256, 0, stream>>>((const unsigned int*)h, als, ald, offs, srcs,
                                  ysl, N);
  k_red<true><<<gRed, 256, 0, stream>>>(ysl, b0, y, stats, N);
  // layer 1 (BN-final + BN+ReLU fused into GEMM A-load)
  k_mfma<32, true><<<gGemm, 256, 0, stream>>>(y, Wt1, as1, ad1, stats, g0, be0,
                                              h, als, ald, N);
  k_gat<<<gGat, 256, 0, stream>>>((const unsigned int*)h, als, ald, offs, srcs,
                                  ysl, N);
  k_red<true><<<gRed, 256, 0, stream>>>(ysl, b1, y, stats + 512, N);
  // layer 2 (head-reduce writes node output directly to d_out)
  k_mfma<32, true><<<gGemm, 256, 0, stream>>>(y, Wt2, as2, ad2, stats + 512, g1, be1,
                                              h, als, ald, N);
  k_gat<<<gGat, 256, 0, stream>>>((const unsigned int*)h, als, ald, offs, srcs,
                                  ysl, N);
  k_red<false><<<gRed, 256, 0, stream>>>(ysl, b2, out_nodes, nullptr, N);
}

// Round 7
// 709.271 us; speedup vs baseline: 1.6552x; 1.6552x over previous
//
#include <hip/hip_runtime.h>
#include <cstdio>
#include <cstdint>

#define LRELU 0.2f
#define BN_EPS 1e-5f

typedef short bf16x8 __attribute__((ext_vector_type(8)));
typedef float f32x4 __attribute__((ext_vector_type(4)));

__device__ inline unsigned short f2bf(float f) {
  unsigned int u = __float_as_uint(f);
  u += 0x7fffu + ((u >> 16) & 1u);   // RNE
  return (unsigned short)(u >> 16);
}
__device__ inline float bf2f(unsigned short v) {
  return __uint_as_float(((unsigned int)v) << 16);
}
__device__ inline float bflo(unsigned int u) { return __uint_as_float(u << 16); }
__device__ inline float bfhi(unsigned int u) { return __uint_as_float(u & 0xffff0000u); }

// device-wide arrival barrier: ctr zeroed by host memset each launch.
// Grid (391 blocks x 256 th) is far below residency capacity -> safe.
__device__ inline void gbar(int* ctr, int target) {
  __syncthreads();
  if (threadIdx.x == 0) {
    __threadfence();
    __hip_atomic_fetch_add(ctr, 1, __ATOMIC_ACQ_REL, __HIP_MEMORY_SCOPE_AGENT);
    while (__hip_atomic_load(ctr, __ATOMIC_ACQUIRE,
                             __HIP_MEMORY_SCOPE_AGENT) < target)
      __builtin_amdgcn_s_sleep(16);
  }
  __syncthreads();
}

// ====== fused CSR build + weight cast (replaces 5 dispatches) ===============
// P0: castW (first 96 block-equivalents) + bucket hist (LDS->global atomics)
//     + edge_attr passthrough copy
// bar1; P1: every block redundantly ex-scans bh[512] in LDS (bsc)
// P2: chunked scatter to bpair using bsc + global bclaim cursors
// bar2; P3: block b = bucket b: LDS hist+scan of 256 dsts -> offs + srcs
__global__ __launch_bounds__(256) void k_build(
    const int* __restrict__ src, const int* __restrict__ dst,
    const float4* __restrict__ ea, float4* __restrict__ oea,
    const float* __restrict__ W0, const float* __restrict__ W1,
    const float* __restrict__ W2,
    unsigned short* __restrict__ Wt0, unsigned short* __restrict__ Wt1,
    unsigned short* __restrict__ Wt2,
    int* __restrict__ bh, int* __restrict__ bclaim,
    uint2* __restrict__ bpair,
    int* __restrict__ offs, int* __restrict__ srcs,
    int* __restrict__ sync, int E, int N, int NB) {
  __shared__ int cnt[512];
  __shared__ int pre[256];
  __shared__ int bsc[513];
  __shared__ int sc[256];
  __shared__ int cur[256];
  const int t = threadIdx.x;
  const int G = gridDim.x;
  const int gid = blockIdx.x * 256 + t;

  // ---- P0a: weight cast+transpose (24576 elems) ----
  if (gid < 24576) {
    int o = gid;
    if (o < 16384) {
      int n = o >> 7, k = o & 127;
      Wt0[o] = f2bf(W0[k * 128 + n]);
    } else if (o < 20480) {
      int p = o - 16384, n = p >> 5, k = p & 31;
      Wt1[p] = f2bf(W1[k * 128 + n]);
    } else {
      int p = o - 20480, n = p >> 5, k = p & 31;
      Wt2[p] = f2bf(W2[k * 128 + n]);
    }
  }

  // ---- P0b: bucket hist over this block's chunk + ea copy ----
  const int chunk = (E + G - 1) / G;
  const int beg = blockIdx.x * chunk;
  const int end = min(E, beg + chunk);
  for (int b = t; b < 512; b += 256) cnt[b] = 0;
  __syncthreads();
  for (int e = beg + t; e < end; e += 256) atomicAdd(&cnt[dst[e] >> 8], 1);
  const int n4 = E * 2;
  for (int i = gid; i < n4; i += G * 256) oea[i] = ea[i];
  __syncthreads();
  for (int b = t; b < 512; b += 256)
    if (cnt[b]) atomicAdd(&bh[b], cnt[b]);

  gbar(&sync[0], G);

  // ---- P1: redundant 512-wide exclusive scan of bh into LDS bsc ----
  const int a0 = bh[2 * t];
  const int a1 = bh[2 * t + 1];
  int s = a0 + a1;
  pre[t] = s;
  __syncthreads();
  for (int st = 1; st < 256; st <<= 1) {
    int u = (t >= st) ? pre[t - st] : 0;
    __syncthreads();
    pre[t] += u;
    __syncthreads();
  }
  const int ex = pre[t] - s;
  bsc[2 * t] = ex;
  bsc[2 * t + 1] = ex + a0;
  if (t == 255) bsc[512] = pre[255];
  __syncthreads();

  // ---- P2: scatter this block's chunk into bpair ----
  for (int b = t; b < 512; b += 256) cnt[b] = 0;
  __syncthreads();
  for (int e = beg + t; e < end; e += 256) atomicAdd(&cnt[dst[e] >> 8], 1);
  __syncthreads();
  for (int b = t; b < 512; b += 256) {
    int c = cnt[b];
    cnt[b] = (c > 0) ? (bsc[b] + atomicAdd(&bclaim[b], c)) : 0;
  }
  __syncthreads();
  for (int e = beg + t; e < end; e += 256) {
    int d = dst[e];
    int pos = atomicAdd(&cnt[d >> 8], 1);
    bpair[pos] = make_uint2((unsigned)src[e], (unsigned)d);
  }

  gbar(&sync[1], G);

  // ---- P3: per-bucket CSR (block b = bucket b) ----
  const int b = blockIdx.x;
  if (b >= NB) return;
  const int lo = b << 8;
  const int e0 = bsc[b], e1 = bsc[b + 1];
  sc[t] = 0;
  __syncthreads();
  for (int e = e0 + t; e < e1; e += 256) atomicAdd(&sc[bpair[e].y & 255], 1);
  __syncthreads();
  int v = sc[t];
  for (int st = 1; st < 256; st <<= 1) {
    int u = (t >= st) ? sc[t - st] : 0;
    __syncthreads();
    sc[t] += u;
    __syncthreads();
  }
  const int pos0 = e0 + sc[t] - v;   // exclusive
  cur[t] = pos0;
  if (lo + t < N) offs[lo + t] = pos0;
  if (b == 0 && t == 0) offs[N] = E;
  __syncthreads();
  for (int e = e0 + t; e < e1; e += 256) {
    uint2 p = bpair[e];
    int pos = atomicAdd(&cur[p.y & 255], 1);
    srcs[pos] = (int)p.x;
  }
}

// ====== MFMA GEMM + fused attention logits (+ optional fused BN+ReLU) =======
template <int K, bool BN>
__global__ __launch_bounds__(256) void k_mfma(
    const float* __restrict__ Ain, const unsigned short* __restrict__ Wt,
    const float* __restrict__ asrc, const float* __restrict__ adst,
    const float* __restrict__ stats, const float* __restrict__ g,
    const float* __restrict__ be,
    unsigned short* __restrict__ h, float* __restrict__ als,
    float* __restrict__ ald, int N) {
  __shared__ unsigned short lsh[4][16 * 132];
  __shared__ float sc_s[32], sh_s[32];
  const int wv   = threadIdx.x >> 6;
  const int lane = threadIdx.x & 63;
  const int quad = lane >> 4;
  const int col  = lane & 15;
  const int m0   = blockIdx.x * 64 + wv * 16;
  const int rowc = min(m0 + col, N - 1);

  if constexpr (BN) {
    if (threadIdx.x < 32) {
      float s = 0.f, ss = 0.f;
#pragma unroll
      for (int r = 0; r < 8; r++) {
        s  += stats[r * 64 + threadIdx.x];
        ss += stats[r * 64 + 32 + threadIdx.x];
      }
      const float inv = 1.f / (float)N;
      const float mu = s * inv;
      const float var = ss * inv - mu * mu;   // biased, as in ref
      const float scv = g[threadIdx.x] * rsqrtf(var + BN_EPS);
      sc_s[threadIdx.x] = scv;
      sh_s[threadIdx.x] = be[threadIdx.x] - mu * scv;
    }
    __syncthreads();
  }

  f32x4 acc[8];
#pragma unroll
  for (int t = 0; t < 8; t++) acc[t] = (f32x4){0.f, 0.f, 0.f, 0.f};

#pragma unroll
  for (int ks = 0; ks < K / 32; ks++) {
    const int k0 = ks * 32 + quad * 8;
    const float* ap = Ain + (size_t)rowc * K + k0;
    float4 f0 = *(const float4*)ap;
    float4 f1 = *(const float4*)(ap + 4);
    bf16x8 a;
    if constexpr (BN) {
      f0.x = fmaxf(0.f, fmaf(f0.x, sc_s[k0 + 0], sh_s[k0 + 0]));
      f0.y = fmaxf(0.f, fmaf(f0.y, sc_s[k0 + 1], sh_s[k0 + 1]));
      f0.z = fmaxf(0.f, fmaf(f0.z, sc_s[k0 + 2], sh_s[k0 + 2]));
      f0.w = fmaxf(0.f, fmaf(f0.w, sc_s[k0 + 3], sh_s[k0 + 3]));
      f1.x = fmaxf(0.f, fmaf(f1.x, sc_s[k0 + 4], sh_s[k0 + 4]));
      f1.y = fmaxf(0.f, fmaf(f1.y, sc_s[k0 + 5], sh_s[k0 + 5]));
      f1.z = fmaxf(0.f, fmaf(f1.z, sc_s[k0 + 6], sh_s[k0 + 6]));
      f1.w = fmaxf(0.f, fmaf(f1.w, sc_s[k0 + 7], sh_s[k0 + 7]));
    }
    a[0] = (short)f2bf(f0.x); a[1] = (short)f2bf(f0.y);
    a[2] = (short)f2bf(f0.z); a[3] = (short)f2bf(f0.w);
    a[4] = (short)f2bf(f1.x); a[5] = (short)f2bf(f1.y);
    a[6] = (short)f2bf(f1.z); a[7] = (short)f2bf(f1.w);
#pragma unroll
    for (int t = 0; t < 8; t++) {
      bf16x8 b = *(const bf16x8*)(Wt + (size_t)(t * 16 + col) * K + k0);
      acc[t] = __builtin_amdgcn_mfma_f32_16x16x32_bf16(a, b, acc[t], 0, 0, 0);
    }
  }

#pragma unroll
  for (int t = 0; t < 8; t++) {
#pragma unroll
    for (int j = 0; j < 4; j++)
      lsh[wv][(quad * 4 + j) * 132 + col + 16 * t] = f2bf(acc[t][j]);
  }
  __syncthreads();

  float as8[8], ad8[8];
#pragma unroll
  for (int j = 0; j < 8; j++) {
    as8[j] = asrc[col * 8 + j];
    ad8[j] = adst[col * 8 + j];
  }

#pragma unroll
  for (int i = 0; i < 4; i++) {
    const int row = i * 4 + quad;
    const int hrow = m0 + row;
    const unsigned short* rp = &lsh[wv][row * 132 + col * 8];
    ushort4 lo = *(const ushort4*)rp;
    ushort4 hi = *(const ushort4*)(rp + 4);
    float p = 0.f, q = 0.f, v;
    v = bf2f(lo.x); p += v * as8[0]; q += v * ad8[0];
    v = bf2f(lo.y); p += v * as8[1]; q += v * ad8[1];
    v = bf2f(lo.z); p += v * as8[2]; q += v * ad8[2];
    v = bf2f(lo.w); p += v * as8[3]; q += v * ad8[3];
    v = bf2f(hi.x); p += v * as8[4]; q += v * ad8[4];
    v = bf2f(hi.y); p += v * as8[5]; q += v * ad8[5];
    v = bf2f(hi.z); p += v * as8[6]; q += v * ad8[6];
    v = bf2f(hi.w); p += v * as8[7]; q += v * ad8[7];
    if (hrow < N) {
      ushort4* gp = (ushort4*)(h + (size_t)hrow * 128 + col * 8);
      gp[0] = lo; gp[1] = hi;
    }
    p += __shfl_xor(p, 1); p += __shfl_xor(p, 2);
    q += __shfl_xor(q, 1); q += __shfl_xor(q, 2);
    if ((lane & 3) == 0 && hrow < N) {
      const int head = col >> 2;
      als[hrow * 4 + head] = p;
      ald[hrow * 4 + head] = q;
    }
  }
}

// ====== per-dst aggregation: 2 edges/wave, software-pipelined gathers =======
// (reverted to the verified R3 structure: 612 us total, k_agg ~95 us/layer,
//  which sits at the measured ~2.4 TB/s fabric floor for 224 MB of L2-miss
//  traffic = NXCD x |h| replication)
template <bool STATS>
__global__ __launch_bounds__(256) void k_agg(
    const unsigned int* __restrict__ h2, const float* __restrict__ als,
    const float* __restrict__ ald, const int* __restrict__ offs,
    const int* __restrict__ srcs, const float* __restrict__ bias,
    float* __restrict__ y, float* __restrict__ stats, int N) {
  __shared__ float s1[32], s2[32];
  const int node = blockIdx.x * 4 + (threadIdx.x >> 6);
  const int lane = threadIdx.x & 63;
  const bool valid = node < N;
  if constexpr (STATS) {
    if (threadIdx.x < 32) { s1[threadIdx.x] = 0.f; s2[threadIdx.x] = 0.f; }
    __syncthreads();
  } else {
    if (!valid) return;
  }

  if (valid) {
    const int half = lane >> 5;        // which edge of a pair
    const int sub  = lane & 31;        // owns channels 4*sub..4*sub+3
    const int head = sub >> 3;
    const int beg = __builtin_amdgcn_readfirstlane(offs[node]);
    const int end = __builtin_amdgcn_readfirstlane(offs[node + 1]);
    const float ad = ald[node * 4 + head];
    float ax0 = 0.f, ax1 = 0.f, ax2 = 0.f, ax3 = 0.f, dn = 0.f;

    for (int base = beg; base < end; base += 64) {
      const int mm = min(64, end - base);
      const int sv = srcs[base + min(lane, mm - 1)];
      const int vlim = mm - half;      // slot i valid iff i < vlim (per-lane)

      float aA0, aA1, aA2, aA3, aB0, aB1, aB2, aB3;
      uint2 uA0, uA1, uA2, uA3, uB0, uB1, uB2, uB3;
      int iA0, iA1, iA2, iA3, iB0, iB1, iB2, iB3;

#define SLOT(S, K, I)                                                      \
  {                                                                        \
    i##S##K = (I);                                                         \
    const int c0 = min((I), mm - 1), c1 = min((I) + 1, mm - 1);            \
    const int sA_ = __builtin_amdgcn_readlane(sv, c0);                     \
    const int sB_ = __builtin_amdgcn_readlane(sv, c1);                     \
    const int s_ = half ? sB_ : sA_;                                       \
    a##S##K = als[s_ * 4 + head];                                          \
    u##S##K = *(const uint2*)(h2 + (size_t)s_ * 64 + (sub << 1));          \
  }
#define ISSUE(S, J0) SLOT(S, 0, (J0)) SLOT(S, 1, (J0) + 2)                 \
                     SLOT(S, 2, (J0) + 4) SLOT(S, 3, (J0) + 6)
#define CSLOT(S, K)                                                        \
  {                                                                        \
    float e_ = a##S##K + ad;                                               \
    e_ = fmaxf(e_, LRELU * e_);                                            \
    float w_ = __expf(e_);                                                 \
    w_ = (i##S##K < vlim) ? w_ : 0.f;                                      \
    dn += w_;                                                              \
    ax0 = fmaf(w_, bflo(u##S##K.x), ax0);                                  \
    ax1 = fmaf(w_, bfhi(u##S##K.x), ax1);                                  \
    ax2 = fmaf(w_, bflo(u##S##K.y), ax2);                                  \
    ax3 = fmaf(w_, bfhi(u##S##K.y), ax3);                                  \
  }
#define COMPUTE(S) CSLOT(S, 0) CSLOT(S, 1) CSLOT(S, 2) CSLOT(S, 3)

      int j0 = 0;
      ISSUE(A, 0)
      j0 = 8;
      if (j0 >= mm) {
        COMPUTE(A)
      } else {
        for (;;) {
          ISSUE(B, j0) COMPUTE(A)
          j0 += 8;
          if (j0 >= mm) { COMPUTE(B) break; }
          ISSUE(A, j0) COMPUTE(B)
          j0 += 8;
          if (j0 >= mm) { COMPUTE(A) break; }
        }
      }
#undef SLOT
#undef ISSUE
#undef CSLOT
#undef COMPUTE
    }

    // per-head denominator: sum the two halves (lane^32 has same head)
    dn += __shfl_xor(dn, 32);
    const float r = (dn > 0.f) ? (1.f / dn) : 0.f;
    ax0 *= r; ax1 *= r; ax2 *= r; ax3 *= r;
    // sum halves, then heads (head bits are lane bits 3,4)
    ax0 += __shfl_xor(ax0, 32); ax1 += __shfl_xor(ax1, 32);
    ax2 += __shfl_xor(ax2, 32); ax3 += __shfl_xor(ax3, 32);
    ax0 += __shfl_xor(ax0, 8);  ax1 += __shfl_xor(ax1, 8);
    ax2 += __shfl_xor(ax2, 8);  ax3 += __shfl_xor(ax3, 8);
    ax0 += __shfl_xor(ax0, 16); ax1 += __shfl_xor(ax1, 16);
    ax2 += __shfl_xor(ax2, 16); ax3 += __shfl_xor(ax3, 16);

    if (lane < 8) {
      float4 b4 = ((const float4*)bias)[lane];
      float4 o;
      o.x = 0.25f * ax0 + b4.x;
      o.y = 0.25f * ax1 + b4.y;
      o.z = 0.25f * ax2 + b4.z;
      o.w = 0.25f * ax3 + b4.w;
      ((float4*)(y + (size_t)node * 32))[lane] = o;
      if constexpr (STATS) {
        atomicAdd(&s1[4 * lane + 0], o.x); atomicAdd(&s2[4 * lane + 0], o.x * o.x);
        atomicAdd(&s1[4 * lane + 1], o.y); atomicAdd(&s2[4 * lane + 1], o.y * o.y);
        atomicAdd(&s1[4 * lane + 2], o.z); atomicAdd(&s2[4 * lane + 2], o.z * o.z);
        atomicAdd(&s1[4 * lane + 3], o.w); atomicAdd(&s2[4 * lane + 3], o.w * o.w);
      }
    }
  }

  if constexpr (STATS) {
    __syncthreads();
    if (threadIdx.x < 32) {
      float* sb = stats + (blockIdx.x & 7) * 64;
      atomicAdd(&sb[threadIdx.x], s1[threadIdx.x]);
      atomicAdd(&sb[32 + threadIdx.x], s2[threadIdx.x]);
    }
  }
}

// ---------------- launch ----------------
extern "C" void kernel_launch(void* const* d_in, const int* in_sizes, int n_in,
                              void* d_out, int out_size, void* d_ws, size_t ws_size,
                              hipStream_t stream) {
  const float* x   = (const float*)d_in[0];
  const int*   ei  = (const int*)d_in[1];
  const float* ea  = (const float*)d_in[2];
  const float* W0  = (const float*)d_in[3];
  const float* as0 = (const float*)d_in[4];
  const float* ad0 = (const float*)d_in[5];
  const float* b0  = (const float*)d_in[6];
  const float* g0  = (const float*)d_in[7];
  const float* be0 = (const float*)d_in[8];
  const float* W1  = (const float*)d_in[9];
  const float* as1 = (const float*)d_in[10];
  const float* ad1 = (const float*)d_in[11];
  const float* b1  = (const float*)d_in[12];
  const float* g1  = (const float*)d_in[13];
  const float* be1 = (const float*)d_in[14];
  const float* W2  = (const float*)d_in[15];
  const float* as2 = (const float*)d_in[16];
  const float* ad2 = (const float*)d_in[17];
  const float* b2  = (const float*)d_in[18];

  const int N = in_sizes[0] / 128;
  const int E = in_sizes[1] / 2;
  const int* srcI = ei;
  const int* dstI = ei + E;
  const int NB = (N + 255) >> 8;

  char* w = (char*)d_ws;
  auto carve = [&](size_t bytes) -> void* {
    void* p = (void*)w;
    w += (bytes + 255) & ~(size_t)255;
    return p;
  };
  unsigned short* h  = (unsigned short*)carve((size_t)N * 128 * 2);
  float* als        = (float*)carve((size_t)N * 4 * 4);
  float* ald        = (float*)carve((size_t)N * 4 * 4);
  float* y          = (float*)carve((size_t)N * 32 * 4);
  int* offs         = (int*)carve((size_t)(N + 1) * 4);
  int* srcs         = (int*)carve((size_t)E * 4);
  // zero-init region: bh + bclaim + stats + sync in ONE small memset
  int* bh           = (int*)carve(512 * 4);
  int* bclaim       = (int*)carve(512 * 4);
  float* stats      = (float*)carve(1024 * 4);   // 2 layers x 8 replicas x 64
  int* syncc        = (int*)carve(16 * 4);
  char* zend        = w;
  unsigned short* Wt0 = (unsigned short*)carve(128 * 128 * 2);
  unsigned short* Wt1 = (unsigned short*)carve(128 * 32 * 2);
  unsigned short* Wt2 = (unsigned short*)carve(128 * 32 * 2);
  if ((size_t)(w - (char*)d_ws) > ws_size) {
    fprintf(stderr, "GAT kernel: ws too small (%zu needed, %zu given)\n",
            (size_t)(w - (char*)d_ws), ws_size);
    return;
  }
  uint2* bpair = (uint2*)h;   // aliases h; consumed before h is written

  float* out_nodes = (float*)d_out;
  float* out_ea    = out_nodes + (size_t)N * 32;

  (void)hipMemsetAsync(bh, 0, (size_t)(zend - (char*)bh), stream);

  // fused CSR build + weight cast + edge_attr passthrough (1 dispatch)
  k_build<<<NB, 256, 0, stream>>>(srcI, dstI, (const float4*)ea,
                                  (float4*)out_ea, W0, W1, W2, Wt0, Wt1, Wt2,
                                  bh, bclaim, bpair, offs, srcs, syncc,
                                  E, N, NB);

  const int gGemm = (N + 63) / 64;
  const int gAgg  = (N + 3) / 4;

  // layer 0
  k_mfma<128, false><<<gGemm, 256, 0, stream>>>(x, Wt0, as0, ad0,
                                                nullptr, nullptr, nullptr,
                                                h, als, ald, N);
  k_agg<true><<<gAgg, 256, 0, stream>>>((const unsigned int*)h, als, ald, offs,
                                        srcs, b0, y, stats, N);
  // layer 1 (BN-final + BN+ReLU fused into GEMM A-load)
  k_mfma<32, true><<<gGemm, 256, 0, stream>>>(y, Wt1, as1, ad1, stats, g0, be0,
                                              h, als, ald, N);
  k_agg<true><<<gAgg, 256, 0, stream>>>((const unsigned int*)h, als, ald, offs,
                                        srcs, b1, y, stats + 512, N);
  // layer 2 (writes node output directly to d_out)
  k_mfma<32, true><<<gGemm, 256, 0, stream>>>(y, Wt2, as2, ad2, stats + 512, g1, be1,
                                              h, als, ald, N);
  k_agg<false><<<gAgg, 256, 0, stream>>>((const unsigned int*)h, als, ald, offs,
                                         srcs, b2, out_nodes, nullptr, N);
}

// Round 10
// 583.933 us; speedup vs baseline: 2.0105x; 1.2146x over previous
//
#include <hip/hip_runtime.h>
#include <cstdio>
#include <cstdint>

#define LRELU 0.2f
#define BN_EPS 1e-5f

typedef short bf16x8 __attribute__((ext_vector_type(8)));
typedef float f32x4 __attribute__((ext_vector_type(4)));

__device__ inline unsigned short f2bf(float f) {
  unsigned int u = __float_as_uint(f);
  u += 0x7fffu + ((u >> 16) & 1u);   // RNE
  return (unsigned short)(u >> 16);
}
__device__ inline float bf2f(unsigned short v) {
  return __uint_as_float(((unsigned int)v) << 16);
}
__device__ inline float bflo(unsigned int u) { return __uint_as_float(u << 16); }
__device__ inline float bfhi(unsigned int u) { return __uint_as_float(u & 0xffff0000u); }

// =========== CSR build (bucketed: bucket = dst>>8, NB = ceil(N/256)) ========
// R7 lesson: k_build fusion collapsed parallelism (391 blocks, 0.8% VALU,
// 587 GB/s) -> 235 us. Split kernels keep per-phase grid sizing.

__global__ __launch_bounds__(256) void k_bhist(const int* __restrict__ dst,
                                               int* __restrict__ bh, int E) {
  __shared__ int cnt[512];
  for (int b = threadIdx.x; b < 512; b += 256) cnt[b] = 0;
  __syncthreads();
  const int gid = blockIdx.x * blockDim.x + threadIdx.x;
  const int gstride = gridDim.x * blockDim.x;
  for (int i = gid; i < E; i += gstride) atomicAdd(&cnt[dst[i] >> 8], 1);
  __syncthreads();
  for (int b = threadIdx.x; b < 512; b += 256)
    if (cnt[b]) atomicAdd(&bh[b], cnt[b]);
}

__global__ __launch_bounds__(512) void k_exscan(const int* __restrict__ bh,
                                                int* __restrict__ bstart,
                                                int* __restrict__ bcur, int n,
                                                int* __restrict__ offsN) {
  __shared__ int sh[512];
  const int t = threadIdx.x;
  int v = (t < n) ? bh[t] : 0;
  sh[t] = v;
  __syncthreads();
  for (int s = 1; s < 512; s <<= 1) {
    int u = (t >= s) ? sh[t - s] : 0;
    __syncthreads();
    sh[t] += u;
    __syncthreads();
  }
  if (t < n) {
    int ex = sh[t] - v;
    bstart[t] = ex;
    bcur[t] = ex;
  }
  if (t == n - 1) {
    bstart[n] = sh[t];
    *offsN = sh[t];
  }
}

__global__ __launch_bounds__(256) void k_bscatter(const int* __restrict__ src,
                                                  const int* __restrict__ dst,
                                                  int* __restrict__ bcur,
                                                  uint2* __restrict__ bpair, int E) {
  __shared__ int cnt[512];
  const int chunk = (E + gridDim.x - 1) / gridDim.x;
  const int beg = blockIdx.x * chunk;
  const int end = min(E, beg + chunk);
  for (int b = threadIdx.x; b < 512; b += 256) cnt[b] = 0;
  __syncthreads();
  for (int e = beg + threadIdx.x; e < end; e += 256)
    atomicAdd(&cnt[dst[e] >> 8], 1);
  __syncthreads();
  for (int b = threadIdx.x; b < 512; b += 256) {
    int c = cnt[b];
    cnt[b] = (c > 0) ? atomicAdd(&bcur[b], c) : 0;
  }
  __syncthreads();
  for (int e = beg + threadIdx.x; e < end; e += 256) {
    int d = dst[e];
    int pos = atomicAdd(&cnt[d >> 8], 1);
    bpair[pos] = make_uint2((unsigned)src[e], (unsigned)d);
  }
}

// per-bucket: LDS hist of 256 dsts -> LDS scan -> offs + placement
__global__ __launch_bounds__(256) void k_bcsr2(const uint2* __restrict__ bpair,
                                               const int* __restrict__ bstart,
                                               int* __restrict__ offs,
                                               int* __restrict__ srcs, int N) {
  __shared__ int sc[256];
  __shared__ int cur[256];
  const int b = blockIdx.x;
  const int lo = b << 8;
  const int t = threadIdx.x;
  const int e0 = bstart[b], e1 = bstart[b + 1];
  sc[t] = 0;
  __syncthreads();
  for (int e = e0 + t; e < e1; e += 256) atomicAdd(&sc[bpair[e].y & 255], 1);
  __syncthreads();
  int v = sc[t];
  for (int s = 1; s < 256; s <<= 1) {
    int u = (t >= s) ? sc[t - s] : 0;
    __syncthreads();
    sc[t] += u;
    __syncthreads();
  }
  const int pos0 = e0 + sc[t] - v;   // exclusive
  cur[t] = pos0;
  if (lo + t < N) offs[lo + t] = pos0;
  __syncthreads();
  for (int e = e0 + t; e < e1; e += 256) {
    uint2 p = bpair[e];
    int pos = atomicAdd(&cur[p.y & 255], 1);
    srcs[pos] = (int)p.x;
  }
}

// ====== weight cast+transpose (all 3 layers, one launch) ====================
__global__ void k_castW3(const float* __restrict__ W0, const float* __restrict__ W1,
                         const float* __restrict__ W2,
                         unsigned short* __restrict__ Wt0,
                         unsigned short* __restrict__ Wt1,
                         unsigned short* __restrict__ Wt2) {
  int o = blockIdx.x * 256 + threadIdx.x;   // 16384 + 4096 + 4096 = 24576
  if (o < 16384) {
    int n = o >> 7, k = o & 127;
    Wt0[o] = f2bf(W0[k * 128 + n]);
  } else if (o < 20480) {
    int p = o - 16384, n = p >> 5, k = p & 31;
    Wt1[p] = f2bf(W1[k * 128 + n]);
  } else if (o < 24576) {
    int p = o - 20480, n = p >> 5, k = p & 31;
    Wt2[p] = f2bf(W2[k * 128 + n]);
  }
}

// ====== MFMA GEMM + fused attention logits (+ optional fused BN+ReLU) =======
template <int K, bool BN>
__global__ __launch_bounds__(256) void k_mfma(
    const float* __restrict__ Ain, const unsigned short* __restrict__ Wt,
    const float* __restrict__ asrc, const float* __restrict__ adst,
    const float* __restrict__ stats, const float* __restrict__ g,
    const float* __restrict__ be,
    unsigned short* __restrict__ h, float* __restrict__ als,
    float* __restrict__ ald, int N) {
  __shared__ unsigned short lsh[4][16 * 132];
  __shared__ float sc_s[32], sh_s[32];
  const int wv   = threadIdx.x >> 6;
  const int lane = threadIdx.x & 63;
  const int quad = lane >> 4;
  const int col  = lane & 15;
  const int m0   = blockIdx.x * 64 + wv * 16;
  const int rowc = min(m0 + col, N - 1);

  if constexpr (BN) {
    if (threadIdx.x < 32) {
      float s = 0.f, ss = 0.f;
#pragma unroll
      for (int r = 0; r < 8; r++) {
        s  += stats[r * 64 + threadIdx.x];
        ss += stats[r * 64 + 32 + threadIdx.x];
      }
      const float inv = 1.f / (float)N;
      const float mu = s * inv;
      const float var = ss * inv - mu * mu;   // biased, as in ref
      const float scv = g[threadIdx.x] * rsqrtf(var + BN_EPS);
      sc_s[threadIdx.x] = scv;
      sh_s[threadIdx.x] = be[threadIdx.x] - mu * scv;
    }
    __syncthreads();
  }

  f32x4 acc[8];
#pragma unroll
  for (int t = 0; t < 8; t++) acc[t] = (f32x4){0.f, 0.f, 0.f, 0.f};

#pragma unroll
  for (int ks = 0; ks < K / 32; ks++) {
    const int k0 = ks * 32 + quad * 8;
    const float* ap = Ain + (size_t)rowc * K + k0;
    float4 f0 = *(const float4*)ap;
    float4 f1 = *(const float4*)(ap + 4);
    bf16x8 a;
    if constexpr (BN) {
      f0.x = fmaxf(0.f, fmaf(f0.x, sc_s[k0 + 0], sh_s[k0 + 0]));
      f0.y = fmaxf(0.f, fmaf(f0.y, sc_s[k0 + 1], sh_s[k0 + 1]));
      f0.z = fmaxf(0.f, fmaf(f0.z, sc_s[k0 + 2], sh_s[k0 + 2]));
      f0.w = fmaxf(0.f, fmaf(f0.w, sc_s[k0 + 3], sh_s[k0 + 3]));
      f1.x = fmaxf(0.f, fmaf(f1.x, sc_s[k0 + 4], sh_s[k0 + 4]));
      f1.y = fmaxf(0.f, fmaf(f1.y, sc_s[k0 + 5], sh_s[k0 + 5]));
      f1.z = fmaxf(0.f, fmaf(f1.z, sc_s[k0 + 6], sh_s[k0 + 6]));
      f1.w = fmaxf(0.f, fmaf(f1.w, sc_s[k0 + 7], sh_s[k0 + 7]));
    }
    a[0] = (short)f2bf(f0.x); a[1] = (short)f2bf(f0.y);
    a[2] = (short)f2bf(f0.z); a[3] = (short)f2bf(f0.w);
    a[4] = (short)f2bf(f1.x); a[5] = (short)f2bf(f1.y);
    a[6] = (short)f2bf(f1.z); a[7] = (short)f2bf(f1.w);
#pragma unroll
    for (int t = 0; t < 8; t++) {
      bf16x8 b = *(const bf16x8*)(Wt + (size_t)(t * 16 + col) * K + k0);
      acc[t] = __builtin_amdgcn_mfma_f32_16x16x32_bf16(a, b, acc[t], 0, 0, 0);
    }
  }

#pragma unroll
  for (int t = 0; t < 8; t++) {
#pragma unroll
    for (int j = 0; j < 4; j++)
      lsh[wv][(quad * 4 + j) * 132 + col + 16 * t] = f2bf(acc[t][j]);
  }
  __syncthreads();

  float as8[8], ad8[8];
#pragma unroll
  for (int j = 0; j < 8; j++) {
    as8[j] = asrc[col * 8 + j];
    ad8[j] = adst[col * 8 + j];
  }

#pragma unroll
  for (int i = 0; i < 4; i++) {
    const int row = i * 4 + quad;
    const int hrow = m0 + row;
    const unsigned short* rp = &lsh[wv][row * 132 + col * 8];
    ushort4 lo = *(const ushort4*)rp;
    ushort4 hi = *(const ushort4*)(rp + 4);
    float p = 0.f, q = 0.f, v;
    v = bf2f(lo.x); p += v * as8[0]; q += v * ad8[0];
    v = bf2f(lo.y); p += v * as8[1]; q += v * ad8[1];
    v = bf2f(lo.z); p += v * as8[2]; q += v * ad8[2];
    v = bf2f(lo.w); p += v * as8[3]; q += v * ad8[3];
    v = bf2f(hi.x); p += v * as8[4]; q += v * ad8[4];
    v = bf2f(hi.y); p += v * as8[5]; q += v * ad8[5];
    v = bf2f(hi.z); p += v * as8[6]; q += v * ad8[6];
    v = bf2f(hi.w); p += v * as8[7]; q += v * ad8[7];
    if (hrow < N) {
      ushort4* gp = (ushort4*)(h + (size_t)hrow * 128 + col * 8);
      gp[0] = lo; gp[1] = hi;
    }
    p += __shfl_xor(p, 1); p += __shfl_xor(p, 2);
    q += __shfl_xor(q, 1); q += __shfl_xor(q, 2);
    if ((lane & 3) == 0 && hrow < N) {
      const int head = col >> 2;
      als[hrow * 4 + head] = p;
      ald[hrow * 4 + head] = q;
    }
  }
}

// ====== per-dst aggregation: 2 edges/wave, software-pipelined gathers =======
// (verified R3 structure; sits at the ~2.5 TB/s fabric/L3 floor for 224 MB of
//  L2-miss traffic = NXCD x |h| replication)
template <bool STATS>
__global__ __launch_bounds__(256) void k_agg(
    const unsigned int* __restrict__ h2, const float* __restrict__ als,
    const float* __restrict__ ald, const int* __restrict__ offs,
    const int* __restrict__ srcs, const float* __restrict__ bias,
    float* __restrict__ y, float* __restrict__ stats, int N) {
  __shared__ float s1[32], s2[32];
  const int node = blockIdx.x * 4 + (threadIdx.x >> 6);
  const int lane = threadIdx.x & 63;
  const bool valid = node < N;
  if constexpr (STATS) {
    if (threadIdx.x < 32) { s1[threadIdx.x] = 0.f; s2[threadIdx.x] = 0.f; }
    __syncthreads();
  } else {
    if (!valid) return;
  }

  if (valid) {
    const int half = lane >> 5;        // which edge of a pair
    const int sub  = lane & 31;        // owns channels 4*sub..4*sub+3
    const int head = sub >> 3;
    const int beg = __builtin_amdgcn_readfirstlane(offs[node]);
    const int end = __builtin_amdgcn_readfirstlane(offs[node + 1]);
    const float ad = ald[node * 4 + head];
    float ax0 = 0.f, ax1 = 0.f, ax2 = 0.f, ax3 = 0.f, dn = 0.f;

    for (int base = beg; base < end; base += 64) {
      const int mm = min(64, end - base);
      const int sv = srcs[base + min(lane, mm - 1)];
      const int vlim = mm - half;      // slot i valid iff i < vlim (per-lane)

      float aA0, aA1, aA2, aA3, aB0, aB1, aB2, aB3;
      uint2 uA0, uA1, uA2, uA3, uB0, uB1, uB2, uB3;
      int iA0, iA1, iA2, iA3, iB0, iB1, iB2, iB3;

#define SLOT(S, K, I)                                                      \
  {                                                                        \
    i##S##K = (I);                                                         \
    const int c0 = min((I), mm - 1), c1 = min((I) + 1, mm - 1);            \
    const int sA_ = __builtin_amdgcn_readlane(sv, c0);                     \
    const int sB_ = __builtin_amdgcn_readlane(sv, c1);                     \
    const int s_ = half ? sB_ : sA_;                                       \
    a##S##K = als[s_ * 4 + head];                                          \
    u##S##K = *(const uint2*)(h2 + (size_t)s_ * 64 + (sub << 1));          \
  }
#define ISSUE(S, J0) SLOT(S, 0, (J0)) SLOT(S, 1, (J0) + 2)                 \
                     SLOT(S, 2, (J0) + 4) SLOT(S, 3, (J0) + 6)
#define CSLOT(S, K)                                                        \
  {                                                                        \
    float e_ = a##S##K + ad;                                               \
    e_ = fmaxf(e_, LRELU * e_);                                            \
    float w_ = __expf(e_);                                                 \
    w_ = (i##S##K < vlim) ? w_ : 0.f;                                      \
    dn += w_;                                                              \
    ax0 = fmaf(w_, bflo(u##S##K.x), ax0);                                  \
    ax1 = fmaf(w_, bfhi(u##S##K.x), ax1);                                  \
    ax2 = fmaf(w_, bflo(u##S##K.y), ax2);                                  \
    ax3 = fmaf(w_, bfhi(u##S##K.y), ax3);                                  \
  }
#define COMPUTE(S) CSLOT(S, 0) CSLOT(S, 1) CSLOT(S, 2) CSLOT(S, 3)

      int j0 = 0;
      ISSUE(A, 0)
      j0 = 8;
      if (j0 >= mm) {
        COMPUTE(A)
      } else {
        for (;;) {
          ISSUE(B, j0) COMPUTE(A)
          j0 += 8;
          if (j0 >= mm) { COMPUTE(B) break; }
          ISSUE(A, j0) COMPUTE(B)
          j0 += 8;
          if (j0 >= mm) { COMPUTE(A) break; }
        }
      }
#undef SLOT
#undef ISSUE
#undef CSLOT
#undef COMPUTE
    }

    // per-head denominator: sum the two halves (lane^32 has same head)
    dn += __shfl_xor(dn, 32);
    const float r = (dn > 0.f) ? (1.f / dn) : 0.f;
    ax0 *= r; ax1 *= r; ax2 *= r; ax3 *= r;
    // sum halves, then heads (head bits are lane bits 3,4)
    ax0 += __shfl_xor(ax0, 32); ax1 += __shfl_xor(ax1, 32);
    ax2 += __shfl_xor(ax2, 32); ax3 += __shfl_xor(ax3, 32);
    ax0 += __shfl_xor(ax0, 8);  ax1 += __shfl_xor(ax1, 8);
    ax2 += __shfl_xor(ax2, 8);  ax3 += __shfl_xor(ax3, 8);
    ax0 += __shfl_xor(ax0, 16); ax1 += __shfl_xor(ax1, 16);
    ax2 += __shfl_xor(ax2, 16); ax3 += __shfl_xor(ax3, 16);

    if (lane < 8) {
      float4 b4 = ((const float4*)bias)[lane];
      float4 o;
      o.x = 0.25f * ax0 + b4.x;
      o.y = 0.25f * ax1 + b4.y;
      o.z = 0.25f * ax2 + b4.z;
      o.w = 0.25f * ax3 + b4.w;
      ((float4*)(y + (size_t)node * 32))[lane] = o;
      if constexpr (STATS) {
        atomicAdd(&s1[4 * lane + 0], o.x); atomicAdd(&s2[4 * lane + 0], o.x * o.x);
        atomicAdd(&s1[4 * lane + 1], o.y); atomicAdd(&s2[4 * lane + 1], o.y * o.y);
        atomicAdd(&s1[4 * lane + 2], o.z); atomicAdd(&s2[4 * lane + 2], o.z * o.z);
        atomicAdd(&s1[4 * lane + 3], o.w); atomicAdd(&s2[4 * lane + 3], o.w * o.w);
      }
    }
  }

  if constexpr (STATS) {
    __syncthreads();
    if (threadIdx.x < 32) {
      float* sb = stats + (blockIdx.x & 7) * 64;
      atomicAdd(&sb[threadIdx.x], s1[threadIdx.x]);
      atomicAdd(&sb[32 + threadIdx.x], s2[threadIdx.x]);
    }
  }
}

__global__ void k_copy4(const float4* __restrict__ s, float4* __restrict__ d, int n) {
  int i = blockIdx.x * blockDim.x + threadIdx.x;
  if (i < n) d[i] = s[i];
}

// ---------------- launch ----------------
extern "C" void kernel_launch(void* const* d_in, const int* in_sizes, int n_in,
                              void* d_out, int out_size, void* d_ws, size_t ws_size,
                              hipStream_t stream) {
  const float* x   = (const float*)d_in[0];
  const int*   ei  = (const int*)d_in[1];
  const float* ea  = (const float*)d_in[2];
  const float* W0  = (const float*)d_in[3];
  const float* as0 = (const float*)d_in[4];
  const float* ad0 = (const float*)d_in[5];
  const float* b0  = (const float*)d_in[6];
  const float* g0  = (const float*)d_in[7];
  const float* be0 = (const float*)d_in[8];
  const float* W1  = (const float*)d_in[9];
  const float* as1 = (const float*)d_in[10];
  const float* ad1 = (const float*)d_in[11];
  const float* b1  = (const float*)d_in[12];
  const float* g1  = (const float*)d_in[13];
  const float* be1 = (const float*)d_in[14];
  const float* W2  = (const float*)d_in[15];
  const float* as2 = (const float*)d_in[16];
  const float* ad2 = (const float*)d_in[17];
  const float* b2  = (const float*)d_in[18];

  const int N = in_sizes[0] / 128;
  const int E = in_sizes[1] / 2;
  const int* srcI = ei;
  const int* dstI = ei + E;
  const int NB = (N + 255) >> 8;

  char* w = (char*)d_ws;
  auto carve = [&](size_t bytes) -> void* {
    void* p = (void*)w;
    w += (bytes + 255) & ~(size_t)255;
    return p;
  };
  unsigned short* h  = (unsigned short*)carve((size_t)N * 128 * 2);
  float* als        = (float*)carve((size_t)N * 4 * 4);
  float* ald        = (float*)carve((size_t)N * 4 * 4);
  float* y          = (float*)carve((size_t)N * 32 * 4);
  int* offs         = (int*)carve((size_t)(N + 1) * 4);
  int* srcs         = (int*)carve((size_t)E * 4);
  // zero-init region: bh + stats covered by ONE small memset (6 KB)
  int* bh           = (int*)carve(512 * 4);
  float* stats      = (float*)carve(1024 * 4);   // 2 layers x 8 replicas x 64
  char* zend        = w;
  int* bstart       = (int*)carve(513 * 4);
  int* bcur         = (int*)carve(512 * 4);
  unsigned short* Wt0 = (unsigned short*)carve(128 * 128 * 2);
  unsigned short* Wt1 = (unsigned short*)carve(128 * 32 * 2);
  unsigned short* Wt2 = (unsigned short*)carve(128 * 32 * 2);
  if ((size_t)(w - (char*)d_ws) > ws_size) {
    fprintf(stderr, "GAT kernel: ws too small (%zu needed, %zu given)\n",
            (size_t)(w - (char*)d_ws), ws_size);
    return;
  }
  uint2* bpair = (uint2*)h;   // aliases h; consumed before h is written

  float* out_nodes = (float*)d_out;
  float* out_ea    = out_nodes + (size_t)N * 32;

  (void)hipMemsetAsync(bh, 0, (size_t)(zend - (char*)bh), stream);

  k_bhist<<<512, 256, 0, stream>>>(dstI, bh, E);
  k_exscan<<<1, 512, 0, stream>>>(bh, bstart, bcur, NB, offs + N);
  k_bscatter<<<384, 256, 0, stream>>>(srcI, dstI, bcur, bpair, E);
  k_bcsr2<<<NB, 256, 0, stream>>>(bpair, bstart, offs, srcs, N);

  k_castW3<<<96, 256, 0, stream>>>(W0, W1, W2, Wt0, Wt1, Wt2);

  const int gGemm = (N + 63) / 64;
  const int gAgg  = (N + 3) / 4;

  // layer 0
  k_mfma<128, false><<<gGemm, 256, 0, stream>>>(x, Wt0, as0, ad0,
                                                nullptr, nullptr, nullptr,
                                                h, als, ald, N);
  k_agg<true><<<gAgg, 256, 0, stream>>>((const unsigned int*)h, als, ald, offs,
                                        srcs, b0, y, stats, N);
  // layer 1 (BN-final + BN+ReLU fused into GEMM A-load)
  k_mfma<32, true><<<gGemm, 256, 0, stream>>>(y, Wt1, as1, ad1, stats, g0, be0,
                                              h, als, ald, N);
  k_agg<true><<<gAgg, 256, 0, stream>>>((const unsigned int*)h, als, ald, offs,
                                        srcs, b1, y, stats + 512, N);
  // layer 2 (writes node output directly to d_out)
  k_mfma<32, true><<<gGemm, 256, 0, stream>>>(y, Wt2, as2, ad2, stats + 512, g1, be1,
                                              h, als, ald, N);
  k_agg<false><<<gAgg, 256, 0, stream>>>((const unsigned int*)h, als, ald, offs,
                                         srcs, b2, out_nodes, nullptr, N);
  // edge_attr passthrough last (big grid; doesn't evict x/h ahead of use)
  const int n4 = E * 2;
  k_copy4<<<(n4 + 255) / 256, 256, 0, stream>>>((const float4*)ea, (float4*)out_ea, n4);
}

// Round 12
// 576.630 us; speedup vs baseline: 2.0359x; 1.0127x over previous
//
#include <hip/hip_runtime.h>
#include <cstdio>
#include <cstdint>

#define LRELU 0.2f
#define BN_EPS 1e-5f

typedef short bf16x8 __attribute__((ext_vector_type(8)));
typedef float f32x4 __attribute__((ext_vector_type(4)));

__device__ inline unsigned short f2bf(float f) {
  unsigned int u = __float_as_uint(f);
  u += 0x7fffu + ((u >> 16) & 1u);   // RNE
  return (unsigned short)(u >> 16);
}
__device__ inline float bf2f(unsigned short v) {
  return __uint_as_float(((unsigned int)v) << 16);
}
__device__ inline float bflo(unsigned int u) { return __uint_as_float(u << 16); }
__device__ inline float bfhi(unsigned int u) { return __uint_as_float(u & 0xffff0000u); }

// =========== CSR build (bucketed: bucket = dst>>8, NB = ceil(N/256)) ========
// R7 lesson: single fused kernel collapses parallelism. Instead: keep split
// kernels with per-phase grids, but (a) fold castW into the hist kernel,
// (b) drop the separate exscan — scatter/bcsr blocks redundantly scan bh[512]
// in LDS (2 KB read; logic verified in R7's k_build, which passed).
// bpair packed to 4 B: (src<<8)|(dst&255), src < 2^24.

__global__ __launch_bounds__(256) void k_bhist_cast(
    const int* __restrict__ dst, int* __restrict__ bh, int E,
    const float* __restrict__ W0, const float* __restrict__ W1,
    const float* __restrict__ W2,
    unsigned short* __restrict__ Wt0, unsigned short* __restrict__ Wt1,
    unsigned short* __restrict__ Wt2) {
  __shared__ int cnt[512];
  const int gid = blockIdx.x * blockDim.x + threadIdx.x;
  // fused weight cast+transpose (24576 elems; independent of hist)
  if (gid < 24576) {
    int o = gid;
    if (o < 16384) {
      int n = o >> 7, k = o & 127;
      Wt0[o] = f2bf(W0[k * 128 + n]);
    } else if (o < 20480) {
      int p = o - 16384, n = p >> 5, k = p & 31;
      Wt1[p] = f2bf(W1[k * 128 + n]);
    } else {
      int p = o - 20480, n = p >> 5, k = p & 31;
      Wt2[p] = f2bf(W2[k * 128 + n]);
    }
  }
  for (int b = threadIdx.x; b < 512; b += 256) cnt[b] = 0;
  __syncthreads();
  const int gstride = gridDim.x * blockDim.x;
  for (int i = gid; i < E; i += gstride) atomicAdd(&cnt[dst[i] >> 8], 1);
  __syncthreads();
  for (int b = threadIdx.x; b < 512; b += 256)
    if (cnt[b]) atomicAdd(&bh[b], cnt[b]);
}

// redundant per-block exclusive scan of bh[512] -> bsc[513] (LDS)
__device__ inline void scan_bh(const int* __restrict__ bh, int* pre, int* bsc) {
  const int t = threadIdx.x;
  const int a0 = bh[2 * t];
  const int a1 = bh[2 * t + 1];
  int s = a0 + a1;
  pre[t] = s;
  __syncthreads();
  for (int st = 1; st < 256; st <<= 1) {
    int u = (t >= st) ? pre[t - st] : 0;
    __syncthreads();
    pre[t] += u;
    __syncthreads();
  }
  const int ex = pre[t] - s;
  bsc[2 * t] = ex;
  bsc[2 * t + 1] = ex + a0;
  if (t == 255) bsc[512] = pre[255];
  __syncthreads();
}

__global__ __launch_bounds__(256) void k_bscatter(const int* __restrict__ src,
                                                  const int* __restrict__ dst,
                                                  const int* __restrict__ bh,
                                                  int* __restrict__ bclaim,
                                                  unsigned int* __restrict__ bpair,
                                                  int E) {
  __shared__ int pre[256];
  __shared__ int bsc[513];
  __shared__ int cnt[512];
  scan_bh(bh, pre, bsc);
  const int chunk = (E + gridDim.x - 1) / gridDim.x;
  const int beg = blockIdx.x * chunk;
  const int end = min(E, beg + chunk);
  for (int b = threadIdx.x; b < 512; b += 256) cnt[b] = 0;
  __syncthreads();
  for (int e = beg + threadIdx.x; e < end; e += 256)
    atomicAdd(&cnt[dst[e] >> 8], 1);
  __syncthreads();
  for (int b = threadIdx.x; b < 512; b += 256) {
    int c = cnt[b];
    cnt[b] = (c > 0) ? (bsc[b] + atomicAdd(&bclaim[b], c)) : 0;
  }
  __syncthreads();
  for (int e = beg + threadIdx.x; e < end; e += 256) {
    int d = dst[e];
    int pos = atomicAdd(&cnt[d >> 8], 1);
    bpair[pos] = ((unsigned)src[e] << 8) | ((unsigned)d & 255u);
  }
}

// per-bucket: LDS hist of 256 dsts -> LDS scan -> offs + placement
__global__ __launch_bounds__(256) void k_bcsr(const unsigned int* __restrict__ bpair,
                                              const int* __restrict__ bh,
                                              int* __restrict__ offs,
                                              int* __restrict__ srcs, int N, int E) {
  __shared__ int pre[256];
  __shared__ int bsc[513];
  __shared__ int sc[256];
  __shared__ int cur[256];
  scan_bh(bh, pre, bsc);
  const int b = blockIdx.x;
  const int lo = b << 8;
  const int t = threadIdx.x;
  const int e0 = bsc[b], e1 = bsc[b + 1];
  sc[t] = 0;
  __syncthreads();
  for (int e = e0 + t; e < e1; e += 256) atomicAdd(&sc[bpair[e] & 255u], 1);
  __syncthreads();
  int v = sc[t];
  for (int s = 1; s < 256; s <<= 1) {
    int u = (t >= s) ? sc[t - s] : 0;
    __syncthreads();
    sc[t] += u;
    __syncthreads();
  }
  const int pos0 = e0 + sc[t] - v;   // exclusive
  cur[t] = pos0;
  if (lo + t < N) offs[lo + t] = pos0;
  if (b == 0 && t == 0) offs[N] = E;
  __syncthreads();
  for (int e = e0 + t; e < e1; e += 256) {
    unsigned int p = bpair[e];
    int pos = atomicAdd(&cur[p & 255u], 1);
    srcs[pos] = (int)(p >> 8);
  }
}

// ====== MFMA GEMM + fused attention logits (+ optional fused BN+ReLU) =======
template <int K, bool BN>
__global__ __launch_bounds__(256) void k_mfma(
    const float* __restrict__ Ain, const unsigned short* __restrict__ Wt,
    const float* __restrict__ asrc, const float* __restrict__ adst,
    const float* __restrict__ stats, const float* __restrict__ g,
    const float* __restrict__ be,
    unsigned short* __restrict__ h, float* __restrict__ als,
    float* __restrict__ ald, int N) {
  __shared__ unsigned short lsh[4][16 * 132];
  __shared__ float sc_s[32], sh_s[32];
  const int wv   = threadIdx.x >> 6;
  const int lane = threadIdx.x & 63;
  const int quad = lane >> 4;
  const int col  = lane & 15;
  const int m0   = blockIdx.x * 64 + wv * 16;
  const int rowc = min(m0 + col, N - 1);

  if constexpr (BN) {
    if (threadIdx.x < 32) {
      float s = 0.f, ss = 0.f;
#pragma unroll
      for (int r = 0; r < 8; r++) {
        s  += stats[r * 64 + threadIdx.x];
        ss += stats[r * 64 + 32 + threadIdx.x];
      }
      const float inv = 1.f / (float)N;
      const float mu = s * inv;
      const float var = ss * inv - mu * mu;   // biased, as in ref
      const float scv = g[threadIdx.x] * rsqrtf(var + BN_EPS);
      sc_s[threadIdx.x] = scv;
      sh_s[threadIdx.x] = be[threadIdx.x] - mu * scv;
    }
    __syncthreads();
  }

  f32x4 acc[8];
#pragma unroll
  for (int t = 0; t < 8; t++) acc[t] = (f32x4){0.f, 0.f, 0.f, 0.f};

#pragma unroll
  for (int ks = 0; ks < K / 32; ks++) {
    const int k0 = ks * 32 + quad * 8;
    const float* ap = Ain + (size_t)rowc * K + k0;
    float4 f0 = *(const float4*)ap;
    float4 f1 = *(const float4*)(ap + 4);
    bf16x8 a;
    if constexpr (BN) {
      f0.x = fmaxf(0.f, fmaf(f0.x, sc_s[k0 + 0], sh_s[k0 + 0]));
      f0.y = fmaxf(0.f, fmaf(f0.y, sc_s[k0 + 1], sh_s[k0 + 1]));
      f0.z = fmaxf(0.f, fmaf(f0.z, sc_s[k0 + 2], sh_s[k0 + 2]));
      f0.w = fmaxf(0.f, fmaf(f0.w, sc_s[k0 + 3], sh_s[k0 + 3]));
      f1.x = fmaxf(0.f, fmaf(f1.x, sc_s[k0 + 4], sh_s[k0 + 4]));
      f1.y = fmaxf(0.f, fmaf(f1.y, sc_s[k0 + 5], sh_s[k0 + 5]));
      f1.z = fmaxf(0.f, fmaf(f1.z, sc_s[k0 + 6], sh_s[k0 + 6]));
      f1.w = fmaxf(0.f, fmaf(f1.w, sc_s[k0 + 7], sh_s[k0 + 7]));
    }
    a[0] = (short)f2bf(f0.x); a[1] = (short)f2bf(f0.y);
    a[2] = (short)f2bf(f0.z); a[3] = (short)f2bf(f0.w);
    a[4] = (short)f2bf(f1.x); a[5] = (short)f2bf(f1.y);
    a[6] = (short)f2bf(f1.z); a[7] = (short)f2bf(f1.w);
#pragma unroll
    for (int t = 0; t < 8; t++) {
      bf16x8 b = *(const bf16x8*)(Wt + (size_t)(t * 16 + col) * K + k0);
      acc[t] = __builtin_amdgcn_mfma_f32_16x16x32_bf16(a, b, acc[t], 0, 0, 0);
    }
  }

#pragma unroll
  for (int t = 0; t < 8; t++) {
#pragma unroll
    for (int j = 0; j < 4; j++)
      lsh[wv][(quad * 4 + j) * 132 + col + 16 * t] = f2bf(acc[t][j]);
  }
  __syncthreads();

  float as8[8], ad8[8];
#pragma unroll
  for (int j = 0; j < 8; j++) {
    as8[j] = asrc[col * 8 + j];
    ad8[j] = adst[col * 8 + j];
  }

#pragma unroll
  for (int i = 0; i < 4; i++) {
    const int row = i * 4 + quad;
    const int hrow = m0 + row;
    const unsigned short* rp = &lsh[wv][row * 132 + col * 8];
    ushort4 lo = *(const ushort4*)rp;
    ushort4 hi = *(const ushort4*)(rp + 4);
    float p = 0.f, q = 0.f, v;
    v = bf2f(lo.x); p += v * as8[0]; q += v * ad8[0];
    v = bf2f(lo.y); p += v * as8[1]; q += v * ad8[1];
    v = bf2f(lo.z); p += v * as8[2]; q += v * ad8[2];
    v = bf2f(lo.w); p += v * as8[3]; q += v * ad8[3];
    v = bf2f(hi.x); p += v * as8[4]; q += v * ad8[4];
    v = bf2f(hi.y); p += v * as8[5]; q += v * ad8[5];
    v = bf2f(hi.z); p += v * as8[6]; q += v * ad8[6];
    v = bf2f(hi.w); p += v * as8[7]; q += v * ad8[7];
    if (hrow < N) {
      ushort4* gp = (ushort4*)(h + (size_t)hrow * 128 + col * 8);
      gp[0] = lo; gp[1] = hi;
    }
    p += __shfl_xor(p, 1); p += __shfl_xor(p, 2);
    q += __shfl_xor(q, 1); q += __shfl_xor(q, 2);
    if ((lane & 3) == 0 && hrow < N) {
      const int head = col >> 2;
      als[hrow * 4 + head] = p;
      ald[hrow * 4 + head] = q;
    }
  }
}

// ====== per-dst aggregation: 2 edges/wave, software-pipelined gathers =======
// FROZEN (verified R3/R10 structure): traffic-bound at ~2.6 TB/s for 224 MB
// of L2-miss traffic (= NXCD x |h| replication); time invariant across three
// inner-loop variants (VALU 49/52/62% all ~94-96 us). Floor ~85 us.
template <bool STATS>
__global__ __launch_bounds__(256) void k_agg(
    const unsigned int* __restrict__ h2, const float* __restrict__ als,
    const float* __restrict__ ald, const int* __restrict__ offs,
    const int* __restrict__ srcs, const float* __restrict__ bias,
    float* __restrict__ y, float* __restrict__ stats, int N) {
  __shared__ float s1[32], s2[32];
  const int node = blockIdx.x * 4 + (threadIdx.x >> 6);
  const int lane = threadIdx.x & 63;
  const bool valid = node < N;
  if constexpr (STATS) {
    if (threadIdx.x < 32) { s1[threadIdx.x] = 0.f; s2[threadIdx.x] = 0.f; }
    __syncthreads();
  } else {
    if (!valid) return;
  }

  if (valid) {
    const int half = lane >> 5;        // which edge of a pair
    const int sub  = lane & 31;        // owns channels 4*sub..4*sub+3
    const int head = sub >> 3;
    const int beg = __builtin_amdgcn_readfirstlane(offs[node]);
    const int end = __builtin_amdgcn_readfirstlane(offs[node + 1]);
    const float ad = ald[node * 4 + head];
    float ax0 = 0.f, ax1 = 0.f, ax2 = 0.f, ax3 = 0.f, dn = 0.f;

    for (int base = beg; base < end; base += 64) {
      const int mm = min(64, end - base);
      const int sv = srcs[base + min(lane, mm - 1)];
      const int vlim = mm - half;      // slot i valid iff i < vlim (per-lane)

      float aA0, aA1, aA2, aA3, aB0, aB1, aB2, aB3;
      uint2 uA0, uA1, uA2, uA3, uB0, uB1, uB2, uB3;
      int iA0, iA1, iA2, iA3, iB0, iB1, iB2, iB3;

#define SLOT(S, K, I)                                                      \
  {                                                                        \
    i##S##K = (I);                                                         \
    const int c0 = min((I), mm - 1), c1 = min((I) + 1, mm - 1);            \
    const int sA_ = __builtin_amdgcn_readlane(sv, c0);                     \
    const int sB_ = __builtin_amdgcn_readlane(sv, c1);                     \
    const int s_ = half ? sB_ : sA_;                                       \
    a##S##K = als[s_ * 4 + head];                                          \
    u##S##K = *(const uint2*)(h2 + (size_t)s_ * 64 + (sub << 1));          \
  }
#define ISSUE(S, J0) SLOT(S, 0, (J0)) SLOT(S, 1, (J0) + 2)                 \
                     SLOT(S, 2, (J0) + 4) SLOT(S, 3, (J0) + 6)
#define CSLOT(S, K)                                                        \
  {                                                                        \
    float e_ = a##S##K + ad;                                               \
    e_ = fmaxf(e_, LRELU * e_);                                            \
    float w_ = __expf(e_);                                                 \
    w_ = (i##S##K < vlim) ? w_ : 0.f;                                      \
    dn += w_;                                                              \
    ax0 = fmaf(w_, bflo(u##S##K.x), ax0);                                  \
    ax1 = fmaf(w_, bfhi(u##S##K.x), ax1);                                  \
    ax2 = fmaf(w_, bflo(u##S##K.y), ax2);                                  \
    ax3 = fmaf(w_, bfhi(u##S##K.y), ax3);                                  \
  }
#define COMPUTE(S) CSLOT(S, 0) CSLOT(S, 1) CSLOT(S, 2) CSLOT(S, 3)

      int j0 = 0;
      ISSUE(A, 0)
      j0 = 8;
      if (j0 >= mm) {
        COMPUTE(A)
      } else {
        for (;;) {
          ISSUE(B, j0) COMPUTE(A)
          j0 += 8;
          if (j0 >= mm) { COMPUTE(B) break; }
          ISSUE(A, j0) COMPUTE(B)
          j0 += 8;
          if (j0 >= mm) { COMPUTE(A) break; }
        }
      }
#undef SLOT
#undef ISSUE
#undef CSLOT
#undef COMPUTE
    }

    // per-head denominator: sum the two halves (lane^32 has same head)
    dn += __shfl_xor(dn, 32);
    const float r = (dn > 0.f) ? (1.f / dn) : 0.f;
    ax0 *= r; ax1 *= r; ax2 *= r; ax3 *= r;
    // sum halves, then heads (head bits are lane bits 3,4)
    ax0 += __shfl_xor(ax0, 32); ax1 += __shfl_xor(ax1, 32);
    ax2 += __shfl_xor(ax2, 32); ax3 += __shfl_xor(ax3, 32);
    ax0 += __shfl_xor(ax0, 8);  ax1 += __shfl_xor(ax1, 8);
    ax2 += __shfl_xor(ax2, 8);  ax3 += __shfl_xor(ax3, 8);
    ax0 += __shfl_xor(ax0, 16); ax1 += __shfl_xor(ax1, 16);
    ax2 += __shfl_xor(ax2, 16); ax3 += __shfl_xor(ax3, 16);

    if (lane < 8) {
      float4 b4 = ((const float4*)bias)[lane];
      float4 o;
      o.x = 0.25f * ax0 + b4.x;
      o.y = 0.25f * ax1 + b4.y;
      o.z = 0.25f * ax2 + b4.z;
      o.w = 0.25f * ax3 + b4.w;
      ((float4*)(y + (size_t)node * 32))[lane] = o;
      if constexpr (STATS) {
        atomicAdd(&s1[4 * lane + 0], o.x); atomicAdd(&s2[4 * lane + 0], o.x * o.x);
        atomicAdd(&s1[4 * lane + 1], o.y); atomicAdd(&s2[4 * lane + 1], o.y * o.y);
        atomicAdd(&s1[4 * lane + 2], o.z); atomicAdd(&s2[4 * lane + 2], o.z * o.z);
        atomicAdd(&s1[4 * lane + 3], o.w); atomicAdd(&s2[4 * lane + 3], o.w * o.w);
      }
    }
  }

  if constexpr (STATS) {
    __syncthreads();
    if (threadIdx.x < 32) {
      float* sb = stats + (blockIdx.x & 7) * 64;
      atomicAdd(&sb[threadIdx.x], s1[threadIdx.x]);
      atomicAdd(&sb[32 + threadIdx.x], s2[threadIdx.x]);
    }
  }
}

// nontemporal builtins need clang ext-vector types, NOT HIP_vector_type
// (R4/R11 compile lesson)
__global__ void k_copy4(const f32x4* __restrict__ s, f32x4* __restrict__ d, int n) {
  int i = blockIdx.x * blockDim.x + threadIdx.x;
  if (i < n) {
    f32x4 v = __builtin_nontemporal_load(&s[i]);
    __builtin_nontemporal_store(v, &d[i]);
  }
}

// ---------------- launch ----------------
extern "C" void kernel_launch(void* const* d_in, const int* in_sizes, int n_in,
                              void* d_out, int out_size, void* d_ws, size_t ws_size,
                              hipStream_t stream) {
  const float* x   = (const float*)d_in[0];
  const int*   ei  = (const int*)d_in[1];
  const float* ea  = (const float*)d_in[2];
  const float* W0  = (const float*)d_in[3];
  const float* as0 = (const float*)d_in[4];
  const float* ad0 = (const float*)d_in[5];
  const float* b0  = (const float*)d_in[6];
  const float* g0  = (const float*)d_in[7];
  const float* be0 = (const float*)d_in[8];
  const float* W1  = (const float*)d_in[9];
  const float* as1 = (const float*)d_in[10];
  const float* ad1 = (const float*)d_in[11];
  const float* b1  = (const float*)d_in[12];
  const float* g1  = (const float*)d_in[13];
  const float* be1 = (const float*)d_in[14];
  const float* W2  = (const float*)d_in[15];
  const float* as2 = (const float*)d_in[16];
  const float* ad2 = (const float*)d_in[17];
  const float* b2  = (const float*)d_in[18];

  const int N = in_sizes[0] / 128;
  const int E = in_sizes[1] / 2;
  const int* srcI = ei;
  const int* dstI = ei + E;
  const int NB = (N + 255) >> 8;

  char* w = (char*)d_ws;
  auto carve = [&](size_t bytes) -> void* {
    void* p = (void*)w;
    w += (bytes + 255) & ~(size_t)255;
    return p;
  };
  unsigned short* h  = (unsigned short*)carve((size_t)N * 128 * 2);
  float* als        = (float*)carve((size_t)N * 4 * 4);
  float* ald        = (float*)carve((size_t)N * 4 * 4);
  float* y          = (float*)carve((size_t)N * 32 * 4);
  int* offs         = (int*)carve((size_t)(N + 1) * 4);
  int* srcs         = (int*)carve((size_t)E * 4);
  // zero-init region: bh + bclaim + stats covered by ONE small memset (8 KB)
  int* bh           = (int*)carve(512 * 4);
  int* bclaim       = (int*)carve(512 * 4);
  float* stats      = (float*)carve(1024 * 4);   // 2 layers x 8 replicas x 64
  char* zend        = w;
  unsigned short* Wt0 = (unsigned short*)carve(128 * 128 * 2);
  unsigned short* Wt1 = (unsigned short*)carve(128 * 32 * 2);
  unsigned short* Wt2 = (unsigned short*)carve(128 * 32 * 2);
  if ((size_t)(w - (char*)d_ws) > ws_size) {
    fprintf(stderr, "GAT kernel: ws too small (%zu needed, %zu given)\n",
            (size_t)(w - (char*)d_ws), ws_size);
    return;
  }
  unsigned int* bpair = (unsigned int*)h;   // aliases h; consumed before h write

  float* out_nodes = (float*)d_out;
  float* out_ea    = out_nodes + (size_t)N * 32;

  (void)hipMemsetAsync(bh, 0, (size_t)(zend - (char*)bh), stream);

  k_bhist_cast<<<512, 256, 0, stream>>>(dstI, bh, E, W0, W1, W2, Wt0, Wt1, Wt2);
  k_bscatter<<<384, 256, 0, stream>>>(srcI, dstI, bh, bclaim, bpair, E);
  k_bcsr<<<NB, 256, 0, stream>>>(bpair, bh, offs, srcs, N, E);

  const int gGemm = (N + 63) / 64;
  const int gAgg  = (N + 3) / 4;

  // layer 0
  k_mfma<128, false><<<gGemm, 256, 0, stream>>>(x, Wt0, as0, ad0,
                                                nullptr, nullptr, nullptr,
                                                h, als, ald, N);
  k_agg<true><<<gAgg, 256, 0, stream>>>((const unsigned int*)h, als, ald, offs,
                                        srcs, b0, y, stats, N);
  // layer 1 (BN-final + BN+ReLU fused into GEMM A-load)
  k_mfma<32, true><<<gGemm, 256, 0, stream>>>(y, Wt1, as1, ad1, stats, g0, be0,
                                              h, als, ald, N);
  k_agg<true><<<gAgg, 256, 0, stream>>>((const unsigned int*)h, als, ald, offs,
                                        srcs, b1, y, stats + 512, N);
  // layer 2 (writes node output directly to d_out)
  k_mfma<32, true><<<gGemm, 256, 0, stream>>>(y, Wt2, as2, ad2, stats + 512, g1, be1,
                                              h, als, ald, N);
  k_agg<false><<<gAgg, 256, 0, stream>>>((const unsigned int*)h, als, ald, offs,
                                         srcs, b2, out_nodes, nullptr, N);
  // edge_attr passthrough last (big grid, nontemporal; no L2/L3 pollution)
  const int n4 = E * 2;
  k_copy4<<<(n4 + 255) / 256, 256, 0, stream>>>((const f32x4*)ea, (f32x4*)out_ea, n4);
}